// Round 4
// baseline (1486.147 us; speedup 1.0000x reference)
//
#include <hip/hip_runtime.h>
#include <math.h>

#define P_ 6
#define B_ 4
#define HD_ 10
#define E_ 12
#define H_ 128
#define W_ 128
#define HW_ 16384

__device__ __forceinline__ float sigm(float x){ return 1.f/(1.f+expf(-x)); }

// ---------------------------------------------------------------------------
// Kernel 1: att_dec / dp_att (written directly into d_out output slots)
// ---------------------------------------------------------------------------
__global__ __launch_bounds__(256) void attn_kernel(
    const float* __restrict__ xp, const float* __restrict__ xh,
    const float* __restrict__ w_att, const float* __restrict__ b_att,
    const float* __restrict__ w_dec, const float* __restrict__ b_dec,
    float* __restrict__ out_att, float* __restrict__ out_dp)
{
  int idx = blockIdx.x*256 + threadIdx.x;       // p*B*HW + b*HW + hw
  int hw = idx & (HW_-1);
  int pb = idx >> 14;
  int b = pb & 3;
  int p = pb >> 2;
  int half = (p>=4) ? 1 : 0;
  const float* xpb = xp + ((size_t)(p*B_+b)*HD_)*HW_ + hw;
  const float* xhb = xh + ((size_t)(half*B_+b)*HD_)*HW_ + hw;
  float da = 0.f, dd = 0.f;
  #pragma unroll
  for (int c=0;c<10;c++){
    float v = xpb[c*HW_];
    float u = xhb[c*HW_];
    da += v * w_att[p*10+c];
    dd += u * w_dec[p*20+c] + v * w_dec[p*20+10+c];
  }
  out_att[idx] = sigm(dd + b_dec[p]);
  out_dp[idx]  = sigm(da + b_att[p]);
}

// ---------------------------------------------------------------------------
// Fused kernel: offset-conv (20->27, 3x3 SAME) + deformable sampling +
// per-tap 20xCO einsum + BN + ReLU, all from one staged LDS tile.
//   - 8x32 pixel tile + halo 2 (12x36 per channel, zero-padded outside image)
//   - offset head computed per-pixel into registers (om_r[28]); tap loop is
//     FULLY unrolled so om_r indexing stays static (else -> scratch, R2 bug)
//   - in-tile test voted wave-uniform via __all() -> rare global fallback is
//     execz-skipped scalar branch
//   - LAYER2 folds a2b = (1-dp[src]) * edge_out * dp[dst]
// LDS: tile 34.56K + w_off 20.16K + w CO*.. (14.4K/8.6K) -> 2 blocks/CU.
// ---------------------------------------------------------------------------
#define TR_ 12     // staged rows  (8 + 2*2 halo)
#define TC_ 36     // staged cols  (32 + 2*2 halo)
template<int CO, int COP, bool LAYER2>
__global__ __launch_bounds__(256) void fused_dcn_kernel(
    const float* __restrict__ xin,      // layer1: xp (gathered); layer2: hbuf
    const int* __restrict__ src, const int* __restrict__ dst,
    const float* __restrict__ w_off, const float* __restrict__ b_off,
    const float* __restrict__ w, const float* __restrict__ sc, const float* __restrict__ bi,
    const float* __restrict__ dp,       // dp_att (layer2 only)
    float* __restrict__ out)
{
  __shared__ __align__(16) float s_woff[20*9*28];      // 20.16 KB [c][k][o pad 28]
  __shared__ __align__(16) float s_w[9*20*COP];        // [t][c][o pad COP]
  __shared__ __align__(16) float s_tile[20*TR_*TC_];   // 34.56 KB
  __shared__ float s_boff[27];

  int e = blockIdx.z, b = blockIdx.y;
  int tid = threadIdx.x;
  int srcv = src[e], dstv = dst[e];

  const float* base_lo; const float* base_hi;
  if (!LAYER2){
    base_lo = xin + ((size_t)(dstv*B_+b)*HD_)*HW_;   // channels 0..9
    base_hi = xin + ((size_t)(srcv*B_+b)*HD_)*HW_;   // channels 10..19
  } else {
    base_lo = xin + ((size_t)(e*B_+b)*20)*HW_;
    base_hi = base_lo + 10*HW_;
  }

  // stage offset-conv weights [c][k][o27 pad28]
  for (int i=tid; i<20*9*28; i+=256){
    int c = i/252; int r = i - c*252; int k = r/28; int o = r - k*28;
    s_woff[i] = (o<27) ? w_off[(((size_t)e*27+o)*20+c)*9+k] : 0.f;
  }
  // stage einsum weights [t][c][o padCOP]
  for (int i=tid; i<9*20*COP; i+=256){
    int k = i/(20*COP); int r = i - k*(20*COP); int c = r/COP; int o = r - c*COP;
    s_w[i] = (o<CO) ? w[(((size_t)e*CO+o)*20+c)*9+k] : 0.f;
  }
  if (tid < 27) s_boff[tid] = b_off[e*27+tid];

  int tyi = blockIdx.x>>2, txi = blockIdx.x&3;   // 16 x 4 tiles of 8x32
  int ty0 = tyi*8, tx0 = txi*32;

  // stage 20ch x 12x36 tile, zero outside image
  for (int i=tid; i<20*TR_*TC_; i+=256){
    int c = i/(TR_*TC_); int r = i - c*(TR_*TC_); int yy = r/TC_; int xx = r - yy*TC_;
    int gy = ty0 - 2 + yy, gx = tx0 - 2 + xx;
    const float* cb = (c<10) ? (base_lo + c*HW_) : (base_hi + (c-10)*HW_);
    float vv = 0.f;
    if ((unsigned)gy < H_ && (unsigned)gx < W_) vv = cb[gy*W_+gx];
    s_tile[i] = vv;
  }
  __syncthreads();

  int py = tid>>5, px = tid&31;
  int h = ty0+py, wc = tx0+px;
  int hw = h*W_ + wc;

  // ---- phase 1: offset head conv at this pixel, accumulated in registers
  float om_r[28];
  #pragma unroll
  for (int o=0;o<28;o++) om_r[o]=0.f;
  for (int c=0;c<20;c++){
    // pixel at tile-local (py+2,px+2); conv tap (ky-1,kx-1) -> (py+1+ky, px+1+kx)
    const float* tcb = &s_tile[c*(TR_*TC_) + (py+1)*TC_ + (px+1)];
    #pragma unroll
    for (int k=0;k<9;k++){
      int ky=k/3, kx=k-ky*3;
      float v = tcb[ky*TC_ + kx];
      const float4* wp = (const float4*)&s_woff[(c*9+k)*28];   // wave-uniform broadcast
      #pragma unroll
      for (int j=0;j<7;j++){
        float4 w4 = wp[j];
        om_r[4*j+0] += v*w4.x;
        om_r[4*j+1] += v*w4.y;
        om_r[4*j+2] += v*w4.z;
        om_r[4*j+3] += v*w4.w;
      }
    }
  }
  #pragma unroll
  for (int o=0;o<27;o++) om_r[o] += s_boff[o];

  // ---- phase 2: deformable sampling + einsum (taps fully unrolled)
  float acc[COP];
  #pragma unroll
  for (int o=0;o<COP;o++) acc[o]=0.f;

  #pragma unroll
  for (int t=0;t<9;t++){
    int ki = t/3, kj = t - ki*3;
    float offy = om_r[2*t];
    float offx = om_r[2*t+1];
    float m = sigm(om_r[18+t]);
    float pyf = (float)(h + ki - 1) + offy;
    float pxf = (float)(wc + kj - 1) + offx;
    float y0f = floorf(pyf), x0f = floorf(pxf);
    float wy = pyf - y0f, wx = pxf - x0f;
    int y0 = (int)y0f, x0 = (int)x0f;
    float w00 = (1.f-wy)*(1.f-wx)*m;
    float w01 = (1.f-wy)*wx     *m;
    float w10 = wy     *(1.f-wx)*m;
    float w11 = wy     *wx      *m;

    int ly = y0 - ty0 + 2, lx = x0 - tx0 + 2;
    bool inTile = ((unsigned)ly <= (unsigned)(TR_-2)) & ((unsigned)lx <= (unsigned)(TC_-2));

    if (__all(inTile)) {
      // fast path (taken ~always): out-of-image texels staged as 0
      const float* tb = s_tile + ly*TC_ + lx;
      #pragma unroll
      for (int c=0;c<20;c++){
        const float* tc = tb + c*(TR_*TC_);
        float vv = w00*tc[0] + w01*tc[1] + w10*tc[TC_] + w11*tc[TC_+1];
        const float4* wp = (const float4*)&s_w[(t*20+c)*COP];
        #pragma unroll
        for (int j=0;j<COP/4;j++){
          float4 w4 = wp[j];
          acc[4*j+0] += vv*w4.x;
          acc[4*j+1] += vv*w4.y;
          acc[4*j+2] += vv*w4.z;
          acc[4*j+3] += vv*w4.w;
        }
      }
    } else {
      // rare wave-uniform fallback: full global gather with validity masks
      int y1 = y0+1, x1 = x0+1;
      float vy0 = (y0>=0 && y0<H_) ? 1.f : 0.f;
      float vy1 = (y1>=0 && y1<H_) ? 1.f : 0.f;
      float vx0 = (x0>=0 && x0<W_) ? 1.f : 0.f;
      float vx1 = (x1>=0 && x1<W_) ? 1.f : 0.f;
      float g00 = w00*vy0*vx0, g01 = w01*vy0*vx1;
      float g10 = w10*vy1*vx0, g11 = w11*vy1*vx1;
      int y0c = min(max(y0,0),H_-1), y1c = min(max(y1,0),H_-1);
      int x0c = min(max(x0,0),W_-1), x1c = min(max(x1,0),W_-1);
      int i00 = y0c*W_+x0c, i01 = y0c*W_+x1c, i10 = y1c*W_+x0c, i11 = y1c*W_+x1c;
      #pragma unroll
      for (int c=0;c<20;c++){
        const float* pc = (c<10) ? (base_lo + c*HW_) : (base_hi + (c-10)*HW_);
        float vv = g00*pc[i00] + g01*pc[i01] + g10*pc[i10] + g11*pc[i11];
        const float4* wp = (const float4*)&s_w[(t*20+c)*COP];
        #pragma unroll
        for (int j=0;j<COP/4;j++){
          float4 w4 = wp[j];
          acc[4*j+0] += vv*w4.x;
          acc[4*j+1] += vv*w4.y;
          acc[4*j+2] += vv*w4.z;
          acc[4*j+3] += vv*w4.w;
        }
      }
    }
  }

  float dfac = 1.f;
  if (LAYER2){
    float ds = dp[((size_t)srcv*B_+b)*HW_ + hw];
    float dd = dp[((size_t)dstv*B_+b)*HW_ + hw];
    dfac = (1.f-ds)*dd;
  }

  float* ob = out + ((size_t)(e*B_+b)*CO)*HW_ + hw;
  #pragma unroll
  for (int o=0;o<CO;o++){
    float r = acc[o]*sc[e*CO+o] + bi[e*CO+o];
    r = fmaxf(r, 0.f);
    if (LAYER2) r *= dfac;
    ob[o*HW_] = r;
  }
}

// ---------------------------------------------------------------------------
// Kernel 6: segment_max over incoming edges + xhp + update matvec + residual
// ---------------------------------------------------------------------------
__global__ __launch_bounds__(256) void update_kernel(
    const float* __restrict__ xp, const float* __restrict__ xh,
    const float* __restrict__ a2b, const int* __restrict__ dst,
    const float* __restrict__ w_u, const float* __restrict__ b_u,
    const float* __restrict__ att_dec, float* __restrict__ out)
{
  __shared__ __align__(16) float s_wu[30*12];   // [c][d pad 12]
  int p = blockIdx.z, b = blockIdx.y;
  int tid = threadIdx.x;
  for (int i=tid; i<360; i+=256){
    int c = i/12; int d = i - c*12;
    s_wu[i] = (d<10) ? w_u[((size_t)p*10+d)*30+c] : 0.f;
  }
  __syncthreads();

  int tyi = blockIdx.x>>3, txi = blockIdx.x&7;
  int py = tid>>4, px = tid&15;
  int hw = (tyi*16+py)*W_ + txi*16+px;
  int half = (p>=4) ? 1 : 0;
  const float* xpb = xp + ((size_t)(p*B_+b)*HD_)*HW_ + hw;
  const float* xhb = xh + ((size_t)(half*B_+b)*HD_)*HW_ + hw;
  float ad = att_dec[((size_t)p*B_+b)*HW_ + hw];

  float in[30];
  #pragma unroll
  for (int c=0;c<10;c++) in[c] = xpb[c*HW_];
  #pragma unroll
  for (int c=0;c<10;c++) in[10+c] = -INFINITY;
  for (int e=0;e<E_;e++){
    if (dst[e]==p){                               // block-uniform branch
      const float* ab = a2b + ((size_t)(e*B_+b)*HD_)*HW_ + hw;
      #pragma unroll
      for (int c=0;c<10;c++) in[10+c] = fmaxf(in[10+c], ab[c*HW_]);
    }
  }
  #pragma unroll
  for (int c=0;c<10;c++) in[20+c] = ad * xhb[c*HW_];

  float acc[12];
  #pragma unroll
  for (int o=0;o<12;o++) acc[o]=0.f;
  #pragma unroll
  for (int c=0;c<30;c++){
    float v = in[c];
    const float4* wp = (const float4*)&s_wu[c*12];
    #pragma unroll
    for (int j=0;j<3;j++){
      float4 w4 = wp[j];
      acc[4*j+0]+=v*w4.x; acc[4*j+1]+=v*w4.y; acc[4*j+2]+=v*w4.z; acc[4*j+3]+=v*w4.w;
    }
  }

  float* ob = out + ((size_t)(p*B_+b)*HD_)*HW_ + hw;
  #pragma unroll
  for (int o=0;o<10;o++){
    float r = acc[o] + b_u[p*10+o];
    ob[o*HW_] = in[o] + fmaxf(r, 0.f);
  }
}

// ---------------------------------------------------------------------------
extern "C" void kernel_launch(void* const* d_in, const int* in_sizes, int n_in,
                              void* d_out, int out_size, void* d_ws, size_t ws_size,
                              hipStream_t stream)
{
  (void)in_sizes; (void)n_in; (void)out_size; (void)ws_size;
  // d_in[0] = p_fea (unused by the reference forward)
  const float* xp     = (const float*)d_in[1];
  const float* xh     = (const float*)d_in[2];
  const int*   src    = (const int*)d_in[3];
  const int*   dst    = (const int*)d_in[4];
  const float* w_off1 = (const float*)d_in[5];
  const float* b_off1 = (const float*)d_in[6];
  const float* w1     = (const float*)d_in[7];
  const float* s1     = (const float*)d_in[8];
  const float* bb1    = (const float*)d_in[9];
  const float* w_off2 = (const float*)d_in[10];
  const float* b_off2 = (const float*)d_in[11];
  const float* w2     = (const float*)d_in[12];
  const float* s2     = (const float*)d_in[13];
  const float* bb2    = (const float*)d_in[14];
  const float* w_att  = (const float*)d_in[15];
  const float* b_att  = (const float*)d_in[16];
  const float* w_dec  = (const float*)d_in[17];
  const float* b_dec  = (const float*)d_in[18];
  const float* w_u    = (const float*)d_in[19];
  const float* b_u    = (const float*)d_in[20];

  float* out_xp  = (float*)d_out;                                   // (6,4,10,128,128)
  float* out_att = out_xp + (size_t)P_*B_*HD_*HW_;                  // (6,4,1,128,128)
  float* out_dp  = out_att + (size_t)P_*B_*HW_;                     // (6,4,1,128,128)

  float* hbuf = (float*)d_ws;                       // E*B*20*HW  (63 MB)
  float* a2b  = hbuf + (size_t)E_*B_*20*HW_;        // E*B*10*HW  (31 MB)

  dim3 blk(256);
  attn_kernel<<<(P_*B_*HW_)/256, blk, 0, stream>>>(xp, xh, w_att, b_att, w_dec, b_dec, out_att, out_dp);

  dim3 ge(64, B_, E_);
  fused_dcn_kernel<20,20,false><<<ge, blk, 0, stream>>>(
      xp,   src, dst, w_off1, b_off1, w1, s1, bb1, nullptr, hbuf);
  fused_dcn_kernel<10,12,true ><<<ge, blk, 0, stream>>>(
      hbuf, src, dst, w_off2, b_off2, w2, s2, bb2, out_dp, a2b);

  dim3 gu(64, B_, P_);
  update_kernel<<<gu, blk, 0, stream>>>(xp, xh, a2b, dst, w_u, b_u, out_att, out_xp);
}

// Round 5
// 1324.261 us; speedup vs baseline: 1.1222x; 1.1222x over previous
//
#include <hip/hip_runtime.h>
#include <math.h>

#define P_ 6
#define B_ 4
#define HD_ 10
#define E_ 12
#define H_ 128
#define W_ 128
#define HW_ 16384

__device__ __forceinline__ float sigm(float x){ return 1.f/(1.f+expf(-x)); }

// ---------------------------------------------------------------------------
// Kernel 1: att_dec / dp_att (written directly into d_out output slots)
// ---------------------------------------------------------------------------
__global__ __launch_bounds__(256) void attn_kernel(
    const float* __restrict__ xp, const float* __restrict__ xh,
    const float* __restrict__ w_att, const float* __restrict__ b_att,
    const float* __restrict__ w_dec, const float* __restrict__ b_dec,
    float* __restrict__ out_att, float* __restrict__ out_dp)
{
  int idx = blockIdx.x*256 + threadIdx.x;       // p*B*HW + b*HW + hw
  int hw = idx & (HW_-1);
  int pb = idx >> 14;
  int b = pb & 3;
  int p = pb >> 2;
  int half = (p>=4) ? 1 : 0;
  const float* xpb = xp + ((size_t)(p*B_+b)*HD_)*HW_ + hw;
  const float* xhb = xh + ((size_t)(half*B_+b)*HD_)*HW_ + hw;
  float da = 0.f, dd = 0.f;
  #pragma unroll
  for (int c=0;c<10;c++){
    float v = xpb[c*HW_];
    float u = xhb[c*HW_];
    da += v * w_att[p*10+c];
    dd += u * w_dec[p*20+c] + v * w_dec[p*20+10+c];
  }
  out_att[idx] = sigm(dd + b_dec[p]);
  out_dp[idx]  = sigm(da + b_att[p]);
}

// ---------------------------------------------------------------------------
// Fused kernel: offset-conv (20->27, 3x3 SAME) + deformable sampling +
// per-tap 20xCO einsum + BN + ReLU, from one staged LDS tile.
//   - 16x16 pixel tile + halo 2 (20x20 per channel, zero-padded outside image)
//   - offset head computed per-pixel into registers (om_r[28]); tap loop
//     FULLY unrolled so om_r indexing stays static (else scratch, R2 bug)
//   - weight LDS is a UNION: phase 1 holds w_off (20.16 KB), then re-staged
//     with the einsum weights after a barrier (saves 14.4 KB -> 3 blocks/CU)
//   - in-tile test voted wave-uniform via __all(); rare fallback does the
//     global gather (execz-skipped scalar branch)
//   - LAYER2 folds a2b = (1-dp[src]) * edge_out * dp[dst]
// LDS total: 31.25K tile + 20.16K union + 108B = ~52.3 KB -> 3 blocks/CU.
// ---------------------------------------------------------------------------
#define TR_ 20     // staged rows  (16 + 2*2 halo)
#define TC_ 20     // staged cols  (16 + 2*2 halo)
template<int CO, int COP, bool LAYER2>
__global__ __launch_bounds__(256) void fused_dcn_kernel(
    const float* __restrict__ xin,      // layer1: xp (gathered); layer2: hbuf
    const int* __restrict__ src, const int* __restrict__ dst,
    const float* __restrict__ w_off, const float* __restrict__ b_off,
    const float* __restrict__ w, const float* __restrict__ sc, const float* __restrict__ bi,
    const float* __restrict__ dp,       // dp_att (layer2 only)
    float* __restrict__ out)
{
  __shared__ __align__(16) float s_wu[20*9*28];        // 20.16 KB union
  __shared__ __align__(16) float s_tile[20*TR_*TC_];   // 31.25 KB
  __shared__ float s_boff[27];

  int e = blockIdx.z, b = blockIdx.y;
  int tid = threadIdx.x;
  int srcv = src[e], dstv = dst[e];

  const float* base_lo; const float* base_hi;
  if (!LAYER2){
    base_lo = xin + ((size_t)(dstv*B_+b)*HD_)*HW_;   // channels 0..9
    base_hi = xin + ((size_t)(srcv*B_+b)*HD_)*HW_;   // channels 10..19
  } else {
    base_lo = xin + ((size_t)(e*B_+b)*20)*HW_;
    base_hi = base_lo + 10*HW_;
  }

  // stage offset-conv weights into union: [c][k][o27 pad28]
  for (int i=tid; i<20*9*28; i+=256){
    int c = i/252; int r = i - c*252; int k = r/28; int o = r - k*28;
    s_wu[i] = (o<27) ? w_off[(((size_t)e*27+o)*20+c)*9+k] : 0.f;
  }
  if (tid < 27) s_boff[tid] = b_off[e*27+tid];

  int tyi = blockIdx.x>>3, txi = blockIdx.x&7;   // 8x8 tiles of 16x16
  int ty0 = tyi*16, tx0 = txi*16;

  // stage 20ch x 20x20 tile, zero outside image
  for (int i=tid; i<20*TR_*TC_; i+=256){
    int c = i/(TR_*TC_); int r = i - c*(TR_*TC_); int yy = r/TC_; int xx = r - yy*TC_;
    int gy = ty0 - 2 + yy, gx = tx0 - 2 + xx;
    const float* cb = (c<10) ? (base_lo + c*HW_) : (base_hi + (c-10)*HW_);
    float vv = 0.f;
    if ((unsigned)gy < H_ && (unsigned)gx < W_) vv = cb[gy*W_+gx];
    s_tile[i] = vv;
  }
  __syncthreads();

  int py = tid>>4, px = tid&15;
  int h = ty0+py, wc = tx0+px;
  int hw = h*W_ + wc;

  // ---- phase 1: offset head conv at this pixel, accumulated in registers
  float om_r[28];
  #pragma unroll
  for (int o=0;o<28;o++) om_r[o]=0.f;
  for (int c=0;c<20;c++){
    // pixel at tile-local (py+2,px+2); conv tap (ky-1,kx-1) -> (py+1+ky, px+1+kx)
    const float* tcb = &s_tile[c*(TR_*TC_) + (py+1)*TC_ + (px+1)];
    #pragma unroll
    for (int k=0;k<9;k++){
      int ky=k/3, kx=k-ky*3;
      float v = tcb[ky*TC_ + kx];
      const float4* wp = (const float4*)&s_wu[(c*9+k)*28];   // wave-uniform broadcast
      #pragma unroll
      for (int j=0;j<7;j++){
        float4 w4 = wp[j];
        om_r[4*j+0] += v*w4.x;
        om_r[4*j+1] += v*w4.y;
        om_r[4*j+2] += v*w4.z;
        om_r[4*j+3] += v*w4.w;
      }
    }
  }
  #pragma unroll
  for (int o=0;o<27;o++) om_r[o] += s_boff[o];

  // ---- re-stage union with einsum weights [t][c][o padCOP]
  __syncthreads();                     // all waves done reading w_off
  for (int i=tid; i<9*20*COP; i+=256){
    int k = i/(20*COP); int r = i - k*(20*COP); int c = r/COP; int o = r - c*COP;
    s_wu[i] = (o<CO) ? w[(((size_t)e*CO+o)*20+c)*9+k] : 0.f;
  }
  __syncthreads();

  // ---- phase 2: deformable sampling + einsum (taps fully unrolled)
  float acc[COP];
  #pragma unroll
  for (int o=0;o<COP;o++) acc[o]=0.f;

  #pragma unroll
  for (int t=0;t<9;t++){
    int ki = t/3, kj = t - ki*3;
    float offy = om_r[2*t];
    float offx = om_r[2*t+1];
    float m = sigm(om_r[18+t]);
    float pyf = (float)(h + ki - 1) + offy;
    float pxf = (float)(wc + kj - 1) + offx;
    float y0f = floorf(pyf), x0f = floorf(pxf);
    float wy = pyf - y0f, wx = pxf - x0f;
    int y0 = (int)y0f, x0 = (int)x0f;
    float w00 = (1.f-wy)*(1.f-wx)*m;
    float w01 = (1.f-wy)*wx     *m;
    float w10 = wy     *(1.f-wx)*m;
    float w11 = wy     *wx      *m;

    int ly = y0 - ty0 + 2, lx = x0 - tx0 + 2;
    bool inTile = ((unsigned)ly <= (unsigned)(TR_-2)) & ((unsigned)lx <= (unsigned)(TC_-2));

    if (__all(inTile)) {
      // fast path (taken ~always): out-of-image texels staged as 0
      const float* tb = s_tile + ly*TC_ + lx;
      #pragma unroll
      for (int c=0;c<20;c++){
        const float* tc = tb + c*(TR_*TC_);
        float vv = w00*tc[0] + w01*tc[1] + w10*tc[TC_] + w11*tc[TC_+1];
        const float4* wp = (const float4*)&s_wu[(t*20+c)*COP];
        #pragma unroll
        for (int j=0;j<COP/4;j++){
          float4 w4 = wp[j];
          acc[4*j+0] += vv*w4.x;
          acc[4*j+1] += vv*w4.y;
          acc[4*j+2] += vv*w4.z;
          acc[4*j+3] += vv*w4.w;
        }
      }
    } else {
      // rare wave-uniform fallback: full global gather with validity masks
      int y1 = y0+1, x1 = x0+1;
      float vy0 = (y0>=0 && y0<H_) ? 1.f : 0.f;
      float vy1 = (y1>=0 && y1<H_) ? 1.f : 0.f;
      float vx0 = (x0>=0 && x0<W_) ? 1.f : 0.f;
      float vx1 = (x1>=0 && x1<W_) ? 1.f : 0.f;
      float g00 = w00*vy0*vx0, g01 = w01*vy0*vx1;
      float g10 = w10*vy1*vx0, g11 = w11*vy1*vx1;
      int y0c = min(max(y0,0),H_-1), y1c = min(max(y1,0),H_-1);
      int x0c = min(max(x0,0),W_-1), x1c = min(max(x1,0),W_-1);
      int i00 = y0c*W_+x0c, i01 = y0c*W_+x1c, i10 = y1c*W_+x0c, i11 = y1c*W_+x1c;
      #pragma unroll
      for (int c=0;c<20;c++){
        const float* pc = (c<10) ? (base_lo + c*HW_) : (base_hi + (c-10)*HW_);
        float vv = g00*pc[i00] + g01*pc[i01] + g10*pc[i10] + g11*pc[i11];
        const float4* wp = (const float4*)&s_wu[(t*20+c)*COP];
        #pragma unroll
        for (int j=0;j<COP/4;j++){
          float4 w4 = wp[j];
          acc[4*j+0] += vv*w4.x;
          acc[4*j+1] += vv*w4.y;
          acc[4*j+2] += vv*w4.z;
          acc[4*j+3] += vv*w4.w;
        }
      }
    }
  }

  float dfac = 1.f;
  if (LAYER2){
    float ds = dp[((size_t)srcv*B_+b)*HW_ + hw];
    float dd = dp[((size_t)dstv*B_+b)*HW_ + hw];
    dfac = (1.f-ds)*dd;
  }

  float* ob = out + ((size_t)(e*B_+b)*CO)*HW_ + hw;
  #pragma unroll
  for (int o=0;o<CO;o++){
    float r = acc[o]*sc[e*CO+o] + bi[e*CO+o];
    r = fmaxf(r, 0.f);
    if (LAYER2) r *= dfac;
    ob[o*HW_] = r;
  }
}

// ---------------------------------------------------------------------------
// Kernel 6: segment_max over incoming edges + xhp + update matvec + residual
// ---------------------------------------------------------------------------
__global__ __launch_bounds__(256) void update_kernel(
    const float* __restrict__ xp, const float* __restrict__ xh,
    const float* __restrict__ a2b, const int* __restrict__ dst,
    const float* __restrict__ w_u, const float* __restrict__ b_u,
    const float* __restrict__ att_dec, float* __restrict__ out)
{
  __shared__ __align__(16) float s_wu[30*12];   // [c][d pad 12]
  int p = blockIdx.z, b = blockIdx.y;
  int tid = threadIdx.x;
  for (int i=tid; i<360; i+=256){
    int c = i/12; int d = i - c*12;
    s_wu[i] = (d<10) ? w_u[((size_t)p*10+d)*30+c] : 0.f;
  }
  __syncthreads();

  int tyi = blockIdx.x>>3, txi = blockIdx.x&7;
  int py = tid>>4, px = tid&15;
  int hw = (tyi*16+py)*W_ + txi*16+px;
  int half = (p>=4) ? 1 : 0;
  const float* xpb = xp + ((size_t)(p*B_+b)*HD_)*HW_ + hw;
  const float* xhb = xh + ((size_t)(half*B_+b)*HD_)*HW_ + hw;
  float ad = att_dec[((size_t)p*B_+b)*HW_ + hw];

  float in[30];
  #pragma unroll
  for (int c=0;c<10;c++) in[c] = xpb[c*HW_];
  #pragma unroll
  for (int c=0;c<10;c++) in[10+c] = -INFINITY;
  for (int e=0;e<E_;e++){
    if (dst[e]==p){                               // block-uniform branch
      const float* ab = a2b + ((size_t)(e*B_+b)*HD_)*HW_ + hw;
      #pragma unroll
      for (int c=0;c<10;c++) in[10+c] = fmaxf(in[10+c], ab[c*HW_]);
    }
  }
  #pragma unroll
  for (int c=0;c<10;c++) in[20+c] = ad * xhb[c*HW_];

  float acc[12];
  #pragma unroll
  for (int o=0;o<12;o++) acc[o]=0.f;
  #pragma unroll
  for (int c=0;c<30;c++){
    float v = in[c];
    const float4* wp = (const float4*)&s_wu[c*12];
    #pragma unroll
    for (int j=0;j<3;j++){
      float4 w4 = wp[j];
      acc[4*j+0]+=v*w4.x; acc[4*j+1]+=v*w4.y; acc[4*j+2]+=v*w4.z; acc[4*j+3]+=v*w4.w;
    }
  }

  float* ob = out + ((size_t)(p*B_+b)*HD_)*HW_ + hw;
  #pragma unroll
  for (int o=0;o<10;o++){
    float r = acc[o] + b_u[p*10+o];
    ob[o*HW_] = in[o] + fmaxf(r, 0.f);
  }
}

// ---------------------------------------------------------------------------
extern "C" void kernel_launch(void* const* d_in, const int* in_sizes, int n_in,
                              void* d_out, int out_size, void* d_ws, size_t ws_size,
                              hipStream_t stream)
{
  (void)in_sizes; (void)n_in; (void)out_size; (void)ws_size;
  // d_in[0] = p_fea (unused by the reference forward)
  const float* xp     = (const float*)d_in[1];
  const float* xh     = (const float*)d_in[2];
  const int*   src    = (const int*)d_in[3];
  const int*   dst    = (const int*)d_in[4];
  const float* w_off1 = (const float*)d_in[5];
  const float* b_off1 = (const float*)d_in[6];
  const float* w1     = (const float*)d_in[7];
  const float* s1     = (const float*)d_in[8];
  const float* bb1    = (const float*)d_in[9];
  const float* w_off2 = (const float*)d_in[10];
  const float* b_off2 = (const float*)d_in[11];
  const float* w2     = (const float*)d_in[12];
  const float* s2     = (const float*)d_in[13];
  const float* bb2    = (const float*)d_in[14];
  const float* w_att  = (const float*)d_in[15];
  const float* b_att  = (const float*)d_in[16];
  const float* w_dec  = (const float*)d_in[17];
  const float* b_dec  = (const float*)d_in[18];
  const float* w_u    = (const float*)d_in[19];
  const float* b_u    = (const float*)d_in[20];

  float* out_xp  = (float*)d_out;                                   // (6,4,10,128,128)
  float* out_att = out_xp + (size_t)P_*B_*HD_*HW_;                  // (6,4,1,128,128)
  float* out_dp  = out_att + (size_t)P_*B_*HW_;                     // (6,4,1,128,128)

  float* hbuf = (float*)d_ws;                       // E*B*20*HW  (63 MB)
  float* a2b  = hbuf + (size_t)E_*B_*20*HW_;        // E*B*10*HW  (31 MB)

  dim3 blk(256);
  attn_kernel<<<(P_*B_*HW_)/256, blk, 0, stream>>>(xp, xh, w_att, b_att, w_dec, b_dec, out_att, out_dp);

  dim3 ge(64, B_, E_);
  fused_dcn_kernel<20,20,false><<<ge, blk, 0, stream>>>(
      xp,   src, dst, w_off1, b_off1, w1, s1, bb1, nullptr, hbuf);
  fused_dcn_kernel<10,12,true ><<<ge, blk, 0, stream>>>(
      hbuf, src, dst, w_off2, b_off2, w2, s2, bb2, out_dp, a2b);

  dim3 gu(64, B_, P_);
  update_kernel<<<gu, blk, 0, stream>>>(xp, xh, a2b, dst, w_u, b_u, out_att, out_xp);
}

// Round 10
// 1273.389 us; speedup vs baseline: 1.1671x; 1.0400x over previous
//
#include <hip/hip_runtime.h>
#include <math.h>

#define P_ 6
#define B_ 4
#define HD_ 10
#define E_ 12
#define H_ 128
#define W_ 128
#define HW_ 16384

__device__ __forceinline__ float sigm(float x){ return 1.f/(1.f+expf(-x)); }

// ---------------------------------------------------------------------------
// Kernel 1: att_dec / dp_att (written directly into d_out output slots)
// ---------------------------------------------------------------------------
__global__ __launch_bounds__(256) void attn_kernel(
    const float* __restrict__ xp, const float* __restrict__ xh,
    const float* __restrict__ w_att, const float* __restrict__ b_att,
    const float* __restrict__ w_dec, const float* __restrict__ b_dec,
    float* __restrict__ out_att, float* __restrict__ out_dp)
{
  int idx = blockIdx.x*256 + threadIdx.x;       // p*B*HW + b*HW + hw
  int hw = idx & (HW_-1);
  int pb = idx >> 14;
  int b = pb & 3;
  int p = pb >> 2;
  int half = (p>=4) ? 1 : 0;
  const float* xpb = xp + ((size_t)(p*B_+b)*HD_)*HW_ + hw;
  const float* xhb = xh + ((size_t)(half*B_+b)*HD_)*HW_ + hw;
  float da = 0.f, dd = 0.f;
  #pragma unroll
  for (int c=0;c<10;c++){
    float v = xpb[c*HW_];
    float u = xhb[c*HW_];
    da += v * w_att[p*10+c];
    dd += u * w_dec[p*20+c] + v * w_dec[p*20+10+c];
  }
  out_att[idx] = sigm(dd + b_dec[p]);
  out_dp[idx]  = sigm(da + b_att[p]);
}

// ---------------------------------------------------------------------------
// Kernel 2/4: 3x3 SAME conv, 20 in-ch -> 27 out-ch (offset+mask head).
// 2 pixels per thread (rows py and py+8 of a 16x32 tile): each weight float4
// LDS broadcast feeds 8 FMAs instead of 4 (halves LDS-read pressure, the R3
// bottleneck), two independent acc chains double ILP. VGPR kept <=128
// (occupancy steps at 64/128/256 per measured m69 — 152-VGPR kernels drop to
// 2 waves/SIMD, the R4/R5 failure).
// ---------------------------------------------------------------------------
template<bool GATHER>
__global__ __launch_bounds__(256) void conv_off_kernel(
    const float* __restrict__ xin,
    const int* __restrict__ src, const int* __restrict__ dst,
    const float* __restrict__ w_off, const float* __restrict__ b_off,
    float* __restrict__ om)
{
  __shared__ __align__(16) float s_in[20*18*34];   // 48.96 KB: 16x32 tile + halo 1
  __shared__ __align__(16) float s_w[20*9*28];     // 20.16 KB: [c][k][o pad 28]
  int e = blockIdx.z, b = blockIdx.y;
  int tid = threadIdx.x;
  int srcv = 0, dstv = 0;
  if (GATHER){ srcv = src[e]; dstv = dst[e]; }

  for (int i=tid; i<20*9*28; i+=256){
    int c = i/252; int r = i - c*252; int k = r/28; int o = r - k*28;
    s_w[i] = (o<27) ? w_off[(((size_t)e*27+o)*20+c)*9+k] : 0.f;
  }

  int tyi = blockIdx.x>>2, txi = blockIdx.x&3;   // 8x4 tiles of 16x32
  int ty0 = tyi*16, tx0 = txi*32;

  // stage 20ch x 18x34 tile (halo 1), zero outside image
  for (int i=tid; i<20*18*34; i+=256){
    int c = i/612; int r = i - c*612; int yy = r/34; int xx = r - yy*34;
    int gy = ty0 - 1 + yy, gx = tx0 - 1 + xx;
    const float* cb;
    if (GATHER){
      int part = (c<10) ? dstv : srcv;
      int cc = (c<10) ? c : c-10;
      cb = xin + ((size_t)(part*B_+b)*HD_ + cc)*HW_;
    } else {
      cb = xin + ((size_t)(e*B_+b)*20 + c)*HW_;
    }
    float v = 0.f;
    if ((unsigned)gy < H_ && (unsigned)gx < W_) v = cb[gy*W_+gx];
    s_in[i] = v;
  }
  __syncthreads();

  int py = tid>>5, px = tid&31;          // pixel rows py and py+8, col px
  float acc0[28], acc1[28];
  #pragma unroll
  for (int o=0;o<28;o++){ acc0[o]=0.f; acc1[o]=0.f; }

  for (int c=0;c<20;c++){
    const float* tcb = &s_in[c*612 + py*34 + px];
    #pragma unroll
    for (int k=0;k<9;k++){
      int ky=k/3, kx=k-ky*3;
      float v0 = tcb[ky*34 + kx];
      float v1 = tcb[(ky+8)*34 + kx];
      const float4* wp = (const float4*)&s_w[(c*9+k)*28];   // wave-uniform broadcast
      #pragma unroll
      for (int j=0;j<7;j++){
        float4 w4 = wp[j];
        acc0[4*j+0] += v0*w4.x; acc1[4*j+0] += v1*w4.x;
        acc0[4*j+1] += v0*w4.y; acc1[4*j+1] += v1*w4.y;
        acc0[4*j+2] += v0*w4.z; acc1[4*j+2] += v1*w4.z;
        acc0[4*j+3] += v0*w4.w; acc1[4*j+3] += v1*w4.w;
      }
    }
  }

  int hw0 = (ty0+py)*W_ + tx0+px;
  float* ob = om + ((size_t)(e*B_+b)*27)*HW_ + hw0;
  #pragma unroll
  for (int o=0;o<27;o++){
    float bo = b_off[e*27+o];
    ob[o*HW_]          = acc0[o] + bo;
    ob[o*HW_ + 8*W_]   = acc1[o] + bo;
  }
}

// ---------------------------------------------------------------------------
// Kernel 3/5: deformable sampling + per-tap 20xCO einsum + BN + ReLU.
// 2 pixels per thread (rows py, py+8 of a 16x32 tile staged with halo 2:
// 20x36 per channel, zero-padded outside image). Per-tap om loads are
// software-pipelined (prefetch t+1 during t). In-tile test voted wave-uniform
// over BOTH pixels via __all(); rare fallback does the global gather.
// LAYER2 folds a2b = (1-dp[src]) * edge_out * dp[dst].
// ---------------------------------------------------------------------------
#define TRD_ 20    // staged rows (16 + 2*2 halo)
#define TCD_ 36    // staged cols (32 + 2*2 halo)
template<int CO, int COP, bool LAYER2>
__global__ __launch_bounds__(256) void deform_kernel(
    const float* __restrict__ xin,      // layer1: xp (gathered); layer2: hbuf
    const float* __restrict__ om,
    const float* __restrict__ w, const float* __restrict__ sc, const float* __restrict__ bi,
    const int* __restrict__ src, const int* __restrict__ dst,
    const float* __restrict__ dp,       // dp_att (layer2 only)
    float* __restrict__ out)
{
  __shared__ __align__(16) float s_w[9*20*COP];          // [t][c][o pad COP]
  __shared__ __align__(16) float s_tile[20*TRD_*TCD_];   // 57.6 KB
  int e = blockIdx.z, b = blockIdx.y;
  int tid = threadIdx.x;
  int srcv = src[e], dstv = dst[e];

  const float* base_lo; const float* base_hi;
  if (!LAYER2){
    base_lo = xin + ((size_t)(dstv*B_+b)*HD_)*HW_;   // channels 0..9
    base_hi = xin + ((size_t)(srcv*B_+b)*HD_)*HW_;   // channels 10..19
  } else {
    base_lo = xin + ((size_t)(e*B_+b)*20)*HW_;
    base_hi = base_lo + 10*HW_;
  }

  for (int i=tid; i<9*20*COP; i+=256){
    int k = i/(20*COP); int r = i - k*(20*COP); int c = r/COP; int o = r - c*COP;
    s_w[i] = (o<CO) ? w[(((size_t)e*CO+o)*20+c)*9+k] : 0.f;
  }

  int tyi = blockIdx.x>>2, txi = blockIdx.x&3;   // 8x4 tiles of 16x32
  int ty0 = tyi*16, tx0 = txi*32;

  // stage 20ch x 20x36 tile (halo 2), zero outside image
  for (int i=tid; i<20*TRD_*TCD_; i+=256){
    int c = i/(TRD_*TCD_); int r = i - c*(TRD_*TCD_); int yy = r/TCD_; int xx = r - yy*TCD_;
    int gy = ty0 - 2 + yy, gx = tx0 - 2 + xx;
    const float* cb = (c<10) ? (base_lo + c*HW_) : (base_hi + (c-10)*HW_);
    float vv = 0.f;
    if ((unsigned)gy < H_ && (unsigned)gx < W_) vv = cb[gy*W_+gx];
    s_tile[i] = vv;
  }
  __syncthreads();

  int py = tid>>5, px = tid&31;          // pixel rows py and py+8, col px
  int h0 = ty0+py, h1 = h0+8, wc = tx0+px;
  int hw0 = h0*W_ + wc;
  const float* omb0 = om + ((size_t)(e*B_+b)*27)*HW_ + hw0;
  const float* omb1 = omb0 + 8*W_;

  float acc0[COP], acc1[COP];
  #pragma unroll
  for (int o=0;o<COP;o++){ acc0[o]=0.f; acc1[o]=0.f; }

  // software pipeline: prefetch tap 0's om values
  float oy0 = omb0[0], ox0 = omb0[HW_], mm0 = omb0[18*HW_];
  float oy1 = omb1[0], ox1 = omb1[HW_], mm1 = omb1[18*HW_];

  #pragma unroll 1
  for (int t=0;t<9;t++){
    float coy0=oy0, cox0=ox0, cm0=mm0, coy1=oy1, cox1=ox1, cm1=mm1;
    if (t<8){   // issue next tap's loads now; latency hides under compute
      oy0 = omb0[(2*t+2)*HW_]; ox0 = omb0[(2*t+3)*HW_]; mm0 = omb0[(19+t)*HW_];
      oy1 = omb1[(2*t+2)*HW_]; ox1 = omb1[(2*t+3)*HW_]; mm1 = omb1[(19+t)*HW_];
    }
    int ki = t/3, kj = t - ki*3;
    float m0 = sigm(cm0), m1 = sigm(cm1);

    float pyf0 = (float)(h0 + ki - 1) + coy0;
    float pxf0 = (float)(wc + kj - 1) + cox0;
    float pyf1 = (float)(h1 + ki - 1) + coy1;
    float pxf1 = (float)(wc + kj - 1) + cox1;
    float y0f0 = floorf(pyf0), x0f0 = floorf(pxf0);
    float y0f1 = floorf(pyf1), x0f1 = floorf(pxf1);
    float wy0 = pyf0 - y0f0, wx0 = pxf0 - x0f0;
    float wy1 = pyf1 - y0f1, wx1 = pxf1 - x0f1;
    int y00 = (int)y0f0, x00 = (int)x0f0;
    int y01 = (int)y0f1, x01 = (int)x0f1;
    float w00_0 = (1.f-wy0)*(1.f-wx0)*m0, w01_0 = (1.f-wy0)*wx0*m0;
    float w10_0 = wy0*(1.f-wx0)*m0,       w11_0 = wy0*wx0*m0;
    float w00_1 = (1.f-wy1)*(1.f-wx1)*m1, w01_1 = (1.f-wy1)*wx1*m1;
    float w10_1 = wy1*(1.f-wx1)*m1,       w11_1 = wy1*wx1*m1;

    int ly0 = y00 - ty0 + 2, lx0 = x00 - tx0 + 2;
    int ly1 = y01 - ty0 + 2, lx1 = x01 - tx0 + 2;
    bool in0 = ((unsigned)ly0 <= (unsigned)(TRD_-2)) & ((unsigned)lx0 <= (unsigned)(TCD_-2));
    bool in1 = ((unsigned)ly1 <= (unsigned)(TRD_-2)) & ((unsigned)lx1 <= (unsigned)(TCD_-2));

    if (__all(in0 & in1)) {
      // fast path (taken ~always): out-of-image texels staged as 0
      const float* tb0 = s_tile + ly0*TCD_ + lx0;
      const float* tb1 = s_tile + ly1*TCD_ + lx1;
      #pragma unroll
      for (int c=0;c<20;c++){
        const float* t0 = tb0 + c*(TRD_*TCD_);
        const float* t1 = tb1 + c*(TRD_*TCD_);
        float v0 = w00_0*t0[0] + w01_0*t0[1] + w10_0*t0[TCD_] + w11_0*t0[TCD_+1];
        float v1 = w00_1*t1[0] + w01_1*t1[1] + w10_1*t1[TCD_] + w11_1*t1[TCD_+1];
        const float4* wp = (const float4*)&s_w[(t*20+c)*COP];
        #pragma unroll
        for (int j=0;j<COP/4;j++){
          float4 w4 = wp[j];
          acc0[4*j+0] += v0*w4.x; acc1[4*j+0] += v1*w4.x;
          acc0[4*j+1] += v0*w4.y; acc1[4*j+1] += v1*w4.y;
          acc0[4*j+2] += v0*w4.z; acc1[4*j+2] += v1*w4.z;
          acc0[4*j+3] += v0*w4.w; acc1[4*j+3] += v1*w4.w;
        }
      }
    } else {
      // rare wave-uniform fallback: full global gather with validity masks
      int y10 = y00+1, x10 = x00+1, y11 = y01+1, x11 = x01+1;
      float g00_0 = w00_0 * ((y00>=0&&y00<H_)?1.f:0.f) * ((x00>=0&&x00<W_)?1.f:0.f);
      float g01_0 = w01_0 * ((y00>=0&&y00<H_)?1.f:0.f) * ((x10>=0&&x10<W_)?1.f:0.f);
      float g10_0 = w10_0 * ((y10>=0&&y10<H_)?1.f:0.f) * ((x00>=0&&x00<W_)?1.f:0.f);
      float g11_0 = w11_0 * ((y10>=0&&y10<H_)?1.f:0.f) * ((x10>=0&&x10<W_)?1.f:0.f);
      float g00_1 = w00_1 * ((y01>=0&&y01<H_)?1.f:0.f) * ((x01>=0&&x01<W_)?1.f:0.f);
      float g01_1 = w01_1 * ((y01>=0&&y01<H_)?1.f:0.f) * ((x11>=0&&x11<W_)?1.f:0.f);
      float g10_1 = w10_1 * ((y11>=0&&y11<H_)?1.f:0.f) * ((x01>=0&&x01<W_)?1.f:0.f);
      float g11_1 = w11_1 * ((y11>=0&&y11<H_)?1.f:0.f) * ((x11>=0&&x11<W_)?1.f:0.f);
      int y00c=min(max(y00,0),H_-1), y10c=min(max(y10,0),H_-1);
      int x00c=min(max(x00,0),W_-1), x10c=min(max(x10,0),W_-1);
      int y01c=min(max(y01,0),H_-1), y11c=min(max(y11,0),H_-1);
      int x01c=min(max(x01,0),W_-1), x11c=min(max(x11,0),W_-1);
      int iA0=y00c*W_+x00c, iB0=y00c*W_+x10c, iC0=y10c*W_+x00c, iD0=y10c*W_+x10c;
      int iA1=y01c*W_+x01c, iB1=y01c*W_+x11c, iC1=y11c*W_+x01c, iD1=y11c*W_+x11c;
      #pragma unroll
      for (int c=0;c<20;c++){
        const float* pc = (c<10) ? (base_lo + c*HW_) : (base_hi + (c-10)*HW_);
        float v0 = g00_0*pc[iA0] + g01_0*pc[iB0] + g10_0*pc[iC0] + g11_0*pc[iD0];
        float v1 = g00_1*pc[iA1] + g01_1*pc[iB1] + g10_1*pc[iC1] + g11_1*pc[iD1];
        const float4* wp = (const float4*)&s_w[(t*20+c)*COP];
        #pragma unroll
        for (int j=0;j<COP/4;j++){
          float4 w4 = wp[j];
          acc0[4*j+0] += v0*w4.x; acc1[4*j+0] += v1*w4.x;
          acc0[4*j+1] += v0*w4.y; acc1[4*j+1] += v1*w4.y;
          acc0[4*j+2] += v0*w4.z; acc1[4*j+2] += v1*w4.z;
          acc0[4*j+3] += v0*w4.w; acc1[4*j+3] += v1*w4.w;
        }
      }
    }
  }

  float dfac0 = 1.f, dfac1 = 1.f;
  if (LAYER2){
    float ds0 = dp[((size_t)srcv*B_+b)*HW_ + hw0];
    float dd0 = dp[((size_t)dstv*B_+b)*HW_ + hw0];
    float ds1 = dp[((size_t)srcv*B_+b)*HW_ + hw0 + 8*W_];
    float dd1 = dp[((size_t)dstv*B_+b)*HW_ + hw0 + 8*W_];
    dfac0 = (1.f-ds0)*dd0;
    dfac1 = (1.f-ds1)*dd1;
  }

  float* ob = out + ((size_t)(e*B_+b)*CO)*HW_ + hw0;
  #pragma unroll
  for (int o=0;o<CO;o++){
    float sco = sc[e*CO+o], bio = bi[e*CO+o];
    float r0 = fmaxf(acc0[o]*sco + bio, 0.f);
    float r1 = fmaxf(acc1[o]*sco + bio, 0.f);
    if (LAYER2){ r0 *= dfac0; r1 *= dfac1; }
    ob[o*HW_]        = r0;
    ob[o*HW_ + 8*W_] = r1;
  }
}

// ---------------------------------------------------------------------------
// Kernel 6: segment_max over incoming edges + xhp + update matvec + residual
// ---------------------------------------------------------------------------
__global__ __launch_bounds__(256) void update_kernel(
    const float* __restrict__ xp, const float* __restrict__ xh,
    const float* __restrict__ a2b, const int* __restrict__ dst,
    const float* __restrict__ w_u, const float* __restrict__ b_u,
    const float* __restrict__ att_dec, float* __restrict__ out)
{
  __shared__ __align__(16) float s_wu[30*12];   // [c][d pad 12]
  int p = blockIdx.z, b = blockIdx.y;
  int tid = threadIdx.x;
  for (int i=tid; i<360; i+=256){
    int c = i/12; int d = i - c*12;
    s_wu[i] = (d<10) ? w_u[((size_t)p*10+d)*30+c] : 0.f;
  }
  __syncthreads();

  int tyi = blockIdx.x>>3, txi = blockIdx.x&7;
  int py = tid>>4, px = tid&15;
  int hw = (tyi*16+py)*W_ + txi*16+px;
  int half = (p>=4) ? 1 : 0;
  const float* xpb = xp + ((size_t)(p*B_+b)*HD_)*HW_ + hw;
  const float* xhb = xh + ((size_t)(half*B_+b)*HD_)*HW_ + hw;
  float ad = att_dec[((size_t)p*B_+b)*HW_ + hw];

  float in[30];
  #pragma unroll
  for (int c=0;c<10;c++) in[c] = xpb[c*HW_];
  #pragma unroll
  for (int c=0;c<10;c++) in[10+c] = -INFINITY;
  for (int e=0;e<E_;e++){
    if (dst[e]==p){                               // block-uniform branch
      const float* ab = a2b + ((size_t)(e*B_+b)*HD_)*HW_ + hw;
      #pragma unroll
      for (int c=0;c<10;c++) in[10+c] = fmaxf(in[10+c], ab[c*HW_]);
    }
  }
  #pragma unroll
  for (int c=0;c<10;c++) in[20+c] = ad * xhb[c*HW_];

  float acc[12];
  #pragma unroll
  for (int o=0;o<12;o++) acc[o]=0.f;
  #pragma unroll
  for (int c=0;c<30;c++){
    float v = in[c];
    const float4* wp = (const float4*)&s_wu[c*12];
    #pragma unroll
    for (int j=0;j<3;j++){
      float4 w4 = wp[j];
      acc[4*j+0]+=v*w4.x; acc[4*j+1]+=v*w4.y; acc[4*j+2]+=v*w4.z; acc[4*j+3]+=v*w4.w;
    }
  }

  float* ob = out + ((size_t)(p*B_+b)*HD_)*HW_ + hw;
  #pragma unroll
  for (int o=0;o<10;o++){
    float r = acc[o] + b_u[p*10+o];
    ob[o*HW_] = in[o] + fmaxf(r, 0.f);
  }
}

// ---------------------------------------------------------------------------
extern "C" void kernel_launch(void* const* d_in, const int* in_sizes, int n_in,
                              void* d_out, int out_size, void* d_ws, size_t ws_size,
                              hipStream_t stream)
{
  (void)in_sizes; (void)n_in; (void)out_size; (void)ws_size;
  // d_in[0] = p_fea (unused by the reference forward)
  const float* xp     = (const float*)d_in[1];
  const float* xh     = (const float*)d_in[2];
  const int*   src    = (const int*)d_in[3];
  const int*   dst    = (const int*)d_in[4];
  const float* w_off1 = (const float*)d_in[5];
  const float* b_off1 = (const float*)d_in[6];
  const float* w1     = (const float*)d_in[7];
  const float* s1     = (const float*)d_in[8];
  const float* bb1    = (const float*)d_in[9];
  const float* w_off2 = (const float*)d_in[10];
  const float* b_off2 = (const float*)d_in[11];
  const float* w2     = (const float*)d_in[12];
  const float* s2     = (const float*)d_in[13];
  const float* bb2    = (const float*)d_in[14];
  const float* w_att  = (const float*)d_in[15];
  const float* b_att  = (const float*)d_in[16];
  const float* w_dec  = (const float*)d_in[17];
  const float* b_dec  = (const float*)d_in[18];
  const float* w_u    = (const float*)d_in[19];
  const float* b_u    = (const float*)d_in[20];

  float* out_xp  = (float*)d_out;                                   // (6,4,10,128,128)
  float* out_att = out_xp + (size_t)P_*B_*HD_*HW_;                  // (6,4,1,128,128)
  float* out_dp  = out_att + (size_t)P_*B_*HW_;                     // (6,4,1,128,128)

  float* om   = (float*)d_ws;                       // E*B*27*HW  (85 MB, reused)
  float* hbuf = om   + (size_t)E_*B_*27*HW_;        // E*B*20*HW  (63 MB)
  float* a2b  = hbuf + (size_t)E_*B_*20*HW_;        // E*B*10*HW  (31 MB)

  dim3 blk(256);
  attn_kernel<<<(P_*B_*HW_)/256, blk, 0, stream>>>(xp, xh, w_att, b_att, w_dec, b_dec, out_att, out_dp);

  dim3 ge(32, B_, E_);   // 8x4 tiles of 16x32
  conv_off_kernel<true ><<<ge, blk, 0, stream>>>(xp,   src, dst, w_off1, b_off1, om);
  deform_kernel<20,20,false><<<ge, blk, 0, stream>>>(xp,   om, w1, s1, bb1, src, dst, nullptr, hbuf);
  conv_off_kernel<false><<<ge, blk, 0, stream>>>(hbuf, src, dst, w_off2, b_off2, om);
  deform_kernel<10,12,true ><<<ge, blk, 0, stream>>>(hbuf, om, w2, s2, bb2, src, dst, out_dp, a2b);

  dim3 gu(64, B_, P_);
  update_kernel<<<gu, blk, 0, stream>>>(xp, xh, a2b, dst, w_u, b_u, out_att, out_xp);
}

// Round 12
// 879.804 us; speedup vs baseline: 1.6892x; 1.4474x over previous
//
#include <hip/hip_runtime.h>
#include <math.h>

#define P_ 6
#define B_ 4
#define HD_ 10
#define E_ 12
#define H_ 128
#define W_ 128
#define HW_ 16384

__device__ __forceinline__ float sigm(float x){ return 1.f/(1.f+expf(-x)); }

// ---------------------------------------------------------------------------
// Kernel 1: att_dec / dp_att (written directly into d_out output slots)
// ---------------------------------------------------------------------------
__global__ __launch_bounds__(256) void attn_kernel(
    const float* __restrict__ xp, const float* __restrict__ xh,
    const float* __restrict__ w_att, const float* __restrict__ b_att,
    const float* __restrict__ w_dec, const float* __restrict__ b_dec,
    float* __restrict__ out_att, float* __restrict__ out_dp)
{
  int idx = blockIdx.x*256 + threadIdx.x;       // p*B*HW + b*HW + hw
  int hw = idx & (HW_-1);
  int pb = idx >> 14;
  int b = pb & 3;
  int p = pb >> 2;
  int half = (p>=4) ? 1 : 0;
  const float* xpb = xp + ((size_t)(p*B_+b)*HD_)*HW_ + hw;
  const float* xhb = xh + ((size_t)(half*B_+b)*HD_)*HW_ + hw;
  float da = 0.f, dd = 0.f;
  #pragma unroll
  for (int c=0;c<10;c++){
    float v = xpb[c*HW_];
    float u = xhb[c*HW_];
    da += v * w_att[p*10+c];
    dd += u * w_dec[p*20+c] + v * w_dec[p*20+10+c];
  }
  out_att[idx] = sigm(dd + b_dec[p]);
  out_dp[idx]  = sigm(da + b_att[p]);
}

// ---------------------------------------------------------------------------
// Kernel 2/4: 3x3 SAME conv, 20 in-ch -> 27 out-ch (offset+mask head).
// CHANNEL-SPLIT staging: two passes of 10 channels each; acc[28] persists in
// registers across passes. LDS = 10ch tile (12.96K) + 10ch weights (10.08K)
// = 23 KB -> ~6 blocks/CU (vs 3 at R3's 46 KB). 1 pixel/thread keeps VGPR
// ~80 (2-pixel variant measured VGPR 144 -> occupancy collapse, R10).
// ---------------------------------------------------------------------------
template<bool GATHER>
__global__ __launch_bounds__(256) void conv_off_kernel(
    const float* __restrict__ xin,
    const int* __restrict__ src, const int* __restrict__ dst,
    const float* __restrict__ w_off, const float* __restrict__ b_off,
    float* __restrict__ om)
{
  __shared__ __align__(16) float s_in[10*18*18];   // 12.96 KB
  __shared__ __align__(16) float s_w[10*9*28];     // 10.08 KB
  int e = blockIdx.z, b = blockIdx.y;
  int tid = threadIdx.x;
  int srcv = 0, dstv = 0;
  if (GATHER){ srcv = src[e]; dstv = dst[e]; }

  int tyi = blockIdx.x>>3, txi = blockIdx.x&7;   // 8x8 tiles of 16x16
  int ty0 = tyi*16, tx0 = txi*16;
  int py = tid>>4, px = tid&15;

  float acc[28];
  #pragma unroll
  for (int o=0;o<28;o++) acc[o]=0.f;

  #pragma unroll 1
  for (int pass=0; pass<2; ++pass){
    if (pass) __syncthreads();     // prior pass compute done before overwrite

    // stage weights for channels pass*10..pass*10+9: [c][k][o pad 28]
    for (int i=tid; i<10*9*28; i+=256){
      int c = i/252; int r = i - c*252; int k = r/28; int o = r - k*28;
      s_w[i] = (o<27) ? w_off[(((size_t)e*27+o)*20 + pass*10 + c)*9+k] : 0.f;
    }
    // stage input tile: 10 ch x 18x18 (halo 1), zero outside image
    for (int i=tid; i<10*324; i+=256){
      int c = i/324; int r = i - c*324; int yy = r/18; int xx = r - yy*18;
      int gy = ty0 - 1 + yy, gx = tx0 - 1 + xx;
      const float* cb;
      if (GATHER){
        int part = pass ? srcv : dstv;       // ch<10 -> dst, ch>=10 -> src
        cb = xin + ((size_t)(part*B_+b)*HD_ + c)*HW_;
      } else {
        cb = xin + ((size_t)(e*B_+b)*20 + pass*10 + c)*HW_;
      }
      float v = 0.f;
      if ((unsigned)gy < H_ && (unsigned)gx < W_) v = cb[gy*W_+gx];
      s_in[i] = v;
    }
    __syncthreads();

    for (int c=0;c<10;c++){
      const float* tcb = &s_in[c*324 + py*18 + px];
      #pragma unroll
      for (int k=0;k<9;k++){
        int ky=k/3, kx=k-ky*3;
        float v = tcb[ky*18 + kx];
        const float4* wp = (const float4*)&s_w[(c*9+k)*28];  // wave-uniform broadcast
        #pragma unroll
        for (int j=0;j<7;j++){
          float4 w4 = wp[j];
          acc[4*j+0] += v*w4.x;
          acc[4*j+1] += v*w4.y;
          acc[4*j+2] += v*w4.z;
          acc[4*j+3] += v*w4.w;
        }
      }
    }
  }

  int hw = (ty0+py)*W_ + tx0+px;
  float* ob = om + ((size_t)(e*B_+b)*27)*HW_ + hw;
  #pragma unroll
  for (int o=0;o<27;o++) ob[o*HW_] = acc[o] + b_off[e*27+o];
}

// ---------------------------------------------------------------------------
// Kernel 3/5: deformable sampling + per-tap 20xCO einsum + BN + ReLU.
// CHANNEL-SPLIT staging: two passes of 10 channels over an 8x32 pixel tile
// (halo 2 -> 12x36/ch, zero-padded). acc[COP] persists across passes.
// LDS = 17.28K tile + 14.4K/8.64K weights -> 31.7/25.9 KB (5-6 blocks/CU vs
// R3's 3). Per-tap om loads software-pipelined; om re-read in pass 2 hits L2
// (HBM at 6.5%, don't care). In-tile test voted wave-uniform via __all();
// rare fallback gathers the 10 current channels from global.
// LAYER2 folds a2b = (1-dp[src]) * edge_out * dp[dst].
// ---------------------------------------------------------------------------
#define TRD_ 12    // staged rows (8 + 2*2 halo)
#define TCD_ 36    // staged cols (32 + 2*2 halo)
template<int CO, int COP, bool LAYER2>
__global__ __launch_bounds__(256) void deform_kernel(
    const float* __restrict__ xin,      // layer1: xp (gathered); layer2: hbuf
    const float* __restrict__ om,
    const float* __restrict__ w, const float* __restrict__ sc, const float* __restrict__ bi,
    const int* __restrict__ src, const int* __restrict__ dst,
    const float* __restrict__ dp,       // dp_att (layer2 only)
    float* __restrict__ out)
{
  __shared__ __align__(16) float s_w[9*20*COP];          // [t][c20][o pad COP]
  __shared__ __align__(16) float s_tile[10*TRD_*TCD_];   // 17.28 KB
  int e = blockIdx.z, b = blockIdx.y;
  int tid = threadIdx.x;
  int srcv = src[e], dstv = dst[e];

  const float* base_lo; const float* base_hi;
  if (!LAYER2){
    base_lo = xin + ((size_t)(dstv*B_+b)*HD_)*HW_;   // channels 0..9
    base_hi = xin + ((size_t)(srcv*B_+b)*HD_)*HW_;   // channels 10..19
  } else {
    base_lo = xin + ((size_t)(e*B_+b)*20)*HW_;
    base_hi = base_lo + 10*HW_;
  }

  // stage einsum weights for ALL 20 channels once: [t][c][o padCOP]
  for (int i=tid; i<9*20*COP; i+=256){
    int k = i/(20*COP); int r = i - k*(20*COP); int c = r/COP; int o = r - c*COP;
    s_w[i] = (o<CO) ? w[(((size_t)e*CO+o)*20+c)*9+k] : 0.f;
  }

  int tyi = blockIdx.x>>2, txi = blockIdx.x&3;   // 16x4 tiles of 8x32
  int ty0 = tyi*8, tx0 = txi*32;

  int py = tid>>5, px = tid&31;
  int h = ty0+py, wc = tx0+px;
  int hw = h*W_ + wc;
  const float* omb = om + ((size_t)(e*B_+b)*27)*HW_ + hw;

  float acc[COP];
  #pragma unroll
  for (int o=0;o<COP;o++) acc[o]=0.f;

  #pragma unroll 1
  for (int pass=0; pass<2; ++pass){
    const float* basep = pass ? base_hi : base_lo;
    if (pass) __syncthreads();     // prior pass compute done before overwrite

    // stage 10 ch x 12x36 tile, zero outside image
    for (int i=tid; i<10*TRD_*TCD_; i+=256){
      int c = i/(TRD_*TCD_); int r = i - c*(TRD_*TCD_); int yy = r/TCD_; int xx = r - yy*TCD_;
      int gy = ty0 - 2 + yy, gx = tx0 - 2 + xx;
      float vv = 0.f;
      if ((unsigned)gy < H_ && (unsigned)gx < W_) vv = basep[c*HW_ + gy*W_+gx];
      s_tile[i] = vv;
    }
    __syncthreads();

    // software pipeline: prefetch tap 0's om values
    float oy = omb[0], ox = omb[HW_], mm = omb[18*HW_];

    #pragma unroll 1
    for (int t=0;t<9;t++){
      float coy=oy, cox=ox, cm=mm;
      if (t<8){   // issue next tap's loads; latency hides under compute
        oy = omb[(2*t+2)*HW_]; ox = omb[(2*t+3)*HW_]; mm = omb[(19+t)*HW_];
      }
      int ki = t/3, kj = t - ki*3;
      float m = sigm(cm);
      float pyf = (float)(h + ki - 1) + coy;
      float pxf = (float)(wc + kj - 1) + cox;
      float y0f = floorf(pyf), x0f = floorf(pxf);
      float wy = pyf - y0f, wx = pxf - x0f;
      int y0 = (int)y0f, x0 = (int)x0f;
      float w00 = (1.f-wy)*(1.f-wx)*m;
      float w01 = (1.f-wy)*wx     *m;
      float w10 = wy     *(1.f-wx)*m;
      float w11 = wy     *wx      *m;

      int ly = y0 - ty0 + 2, lx = x0 - tx0 + 2;
      bool inTile = ((unsigned)ly <= (unsigned)(TRD_-2)) & ((unsigned)lx <= (unsigned)(TCD_-2));

      if (__all(inTile)) {
        // fast path (taken ~always): out-of-image texels staged as 0
        const float* tb = s_tile + ly*TCD_ + lx;
        #pragma unroll
        for (int c=0;c<10;c++){
          const float* tc = tb + c*(TRD_*TCD_);
          float vv = w00*tc[0] + w01*tc[1] + w10*tc[TCD_] + w11*tc[TCD_+1];
          const float4* wp = (const float4*)&s_w[(t*20 + pass*10 + c)*COP];
          #pragma unroll
          for (int j=0;j<COP/4;j++){
            float4 w4 = wp[j];
            acc[4*j+0] += vv*w4.x;
            acc[4*j+1] += vv*w4.y;
            acc[4*j+2] += vv*w4.z;
            acc[4*j+3] += vv*w4.w;
          }
        }
      } else {
        // rare wave-uniform fallback: global gather with validity masks
        int y1 = y0+1, x1 = x0+1;
        float vy0 = (y0>=0 && y0<H_) ? 1.f : 0.f;
        float vy1 = (y1>=0 && y1<H_) ? 1.f : 0.f;
        float vx0 = (x0>=0 && x0<W_) ? 1.f : 0.f;
        float vx1 = (x1>=0 && x1<W_) ? 1.f : 0.f;
        float g00 = w00*vy0*vx0, g01 = w01*vy0*vx1;
        float g10 = w10*vy1*vx0, g11 = w11*vy1*vx1;
        int y0c = min(max(y0,0),H_-1), y1c = min(max(y1,0),H_-1);
        int x0c = min(max(x0,0),W_-1), x1c = min(max(x1,0),W_-1);
        int i00 = y0c*W_+x0c, i01 = y0c*W_+x1c, i10 = y1c*W_+x0c, i11 = y1c*W_+x1c;
        #pragma unroll
        for (int c=0;c<10;c++){
          const float* pc = basep + c*HW_;
          float vv = g00*pc[i00] + g01*pc[i01] + g10*pc[i10] + g11*pc[i11];
          const float4* wp = (const float4*)&s_w[(t*20 + pass*10 + c)*COP];
          #pragma unroll
          for (int j=0;j<COP/4;j++){
            float4 w4 = wp[j];
            acc[4*j+0] += vv*w4.x;
            acc[4*j+1] += vv*w4.y;
            acc[4*j+2] += vv*w4.z;
            acc[4*j+3] += vv*w4.w;
          }
        }
      }
    }
  }

  float dfac = 1.f;
  if (LAYER2){
    float ds = dp[((size_t)srcv*B_+b)*HW_ + hw];
    float dd = dp[((size_t)dstv*B_+b)*HW_ + hw];
    dfac = (1.f-ds)*dd;
  }

  float* ob = out + ((size_t)(e*B_+b)*CO)*HW_ + hw;
  #pragma unroll
  for (int o=0;o<CO;o++){
    float r = acc[o]*sc[e*CO+o] + bi[e*CO+o];
    r = fmaxf(r, 0.f);
    if (LAYER2) r *= dfac;
    ob[o*HW_] = r;
  }
}

// ---------------------------------------------------------------------------
// Kernel 6: segment_max over incoming edges + xhp + update matvec + residual
// ---------------------------------------------------------------------------
__global__ __launch_bounds__(256) void update_kernel(
    const float* __restrict__ xp, const float* __restrict__ xh,
    const float* __restrict__ a2b, const int* __restrict__ dst,
    const float* __restrict__ w_u, const float* __restrict__ b_u,
    const float* __restrict__ att_dec, float* __restrict__ out)
{
  __shared__ __align__(16) float s_wu[30*12];   // [c][d pad 12]
  int p = blockIdx.z, b = blockIdx.y;
  int tid = threadIdx.x;
  for (int i=tid; i<360; i+=256){
    int c = i/12; int d = i - c*12;
    s_wu[i] = (d<10) ? w_u[((size_t)p*10+d)*30+c] : 0.f;
  }
  __syncthreads();

  int tyi = blockIdx.x>>3, txi = blockIdx.x&7;
  int py = tid>>4, px = tid&15;
  int hw = (tyi*16+py)*W_ + txi*16+px;
  int half = (p>=4) ? 1 : 0;
  const float* xpb = xp + ((size_t)(p*B_+b)*HD_)*HW_ + hw;
  const float* xhb = xh + ((size_t)(half*B_+b)*HD_)*HW_ + hw;
  float ad = att_dec[((size_t)p*B_+b)*HW_ + hw];

  float in[30];
  #pragma unroll
  for (int c=0;c<10;c++) in[c] = xpb[c*HW_];
  #pragma unroll
  for (int c=0;c<10;c++) in[10+c] = -INFINITY;
  for (int e=0;e<E_;e++){
    if (dst[e]==p){                               // block-uniform branch
      const float* ab = a2b + ((size_t)(e*B_+b)*HD_)*HW_ + hw;
      #pragma unroll
      for (int c=0;c<10;c++) in[10+c] = fmaxf(in[10+c], ab[c*HW_]);
    }
  }
  #pragma unroll
  for (int c=0;c<10;c++) in[20+c] = ad * xhb[c*HW_];

  float acc[12];
  #pragma unroll
  for (int o=0;o<12;o++) acc[o]=0.f;
  #pragma unroll
  for (int c=0;c<30;c++){
    float v = in[c];
    const float4* wp = (const float4*)&s_wu[c*12];
    #pragma unroll
    for (int j=0;j<3;j++){
      float4 w4 = wp[j];
      acc[4*j+0]+=v*w4.x; acc[4*j+1]+=v*w4.y; acc[4*j+2]+=v*w4.z; acc[4*j+3]+=v*w4.w;
    }
  }

  float* ob = out + ((size_t)(p*B_+b)*HD_)*HW_ + hw;
  #pragma unroll
  for (int o=0;o<10;o++){
    float r = acc[o] + b_u[p*10+o];
    ob[o*HW_] = in[o] + fmaxf(r, 0.f);
  }
}

// ---------------------------------------------------------------------------
extern "C" void kernel_launch(void* const* d_in, const int* in_sizes, int n_in,
                              void* d_out, int out_size, void* d_ws, size_t ws_size,
                              hipStream_t stream)
{
  (void)in_sizes; (void)n_in; (void)out_size; (void)ws_size;
  // d_in[0] = p_fea (unused by the reference forward)
  const float* xp     = (const float*)d_in[1];
  const float* xh     = (const float*)d_in[2];
  const int*   src    = (const int*)d_in[3];
  const int*   dst    = (const int*)d_in[4];
  const float* w_off1 = (const float*)d_in[5];
  const float* b_off1 = (const float*)d_in[6];
  const float* w1     = (const float*)d_in[7];
  const float* s1     = (const float*)d_in[8];
  const float* bb1    = (const float*)d_in[9];
  const float* w_off2 = (const float*)d_in[10];
  const float* b_off2 = (const float*)d_in[11];
  const float* w2     = (const float*)d_in[12];
  const float* s2     = (const float*)d_in[13];
  const float* bb2    = (const float*)d_in[14];
  const float* w_att  = (const float*)d_in[15];
  const float* b_att  = (const float*)d_in[16];
  const float* w_dec  = (const float*)d_in[17];
  const float* b_dec  = (const float*)d_in[18];
  const float* w_u    = (const float*)d_in[19];
  const float* b_u    = (const float*)d_in[20];

  float* out_xp  = (float*)d_out;                                   // (6,4,10,128,128)
  float* out_att = out_xp + (size_t)P_*B_*HD_*HW_;                  // (6,4,1,128,128)
  float* out_dp  = out_att + (size_t)P_*B_*HW_;                     // (6,4,1,128,128)

  float* om   = (float*)d_ws;                       // E*B*27*HW  (85 MB, reused)
  float* hbuf = om   + (size_t)E_*B_*27*HW_;        // E*B*20*HW  (63 MB)
  float* a2b  = hbuf + (size_t)E_*B_*20*HW_;        // E*B*10*HW  (31 MB)

  dim3 blk(256);
  attn_kernel<<<(P_*B_*HW_)/256, blk, 0, stream>>>(xp, xh, w_att, b_att, w_dec, b_dec, out_att, out_dp);

  dim3 gc(64, B_, E_);   // 8x8 tiles of 16x16
  dim3 gd(64, B_, E_);   // 16x4 tiles of 8x32
  conv_off_kernel<true ><<<gc, blk, 0, stream>>>(xp,   src, dst, w_off1, b_off1, om);
  deform_kernel<20,20,false><<<gd, blk, 0, stream>>>(xp,   om, w1, s1, bb1, src, dst, nullptr, hbuf);
  conv_off_kernel<false><<<gc, blk, 0, stream>>>(hbuf, src, dst, w_off2, b_off2, om);
  deform_kernel<10,12,true ><<<gd, blk, 0, stream>>>(hbuf, om, w2, s2, bb2, src, dst, out_dp, a2b);

  dim3 gu(64, B_, P_);
  update_kernel<<<gu, blk, 0, stream>>>(xp, xh, a2b, dst, w_u, b_u, out_att, out_xp);
}